// Round 10
// baseline (254.590 us; speedup 1.0000x reference)
//
#include <hip/hip_runtime.h>
#include <stdint.h>

#define NB 4
#define NS 2048
#define NE 1024
#define NH 16
#define ND 64

typedef __attribute__((ext_vector_type(8))) short short8;
typedef __attribute__((ext_vector_type(2))) float f32x2;
typedef __attribute__((ext_vector_type(4))) float f32x4;
typedef __attribute__((ext_vector_type(8))) float f32x8;
typedef __attribute__((ext_vector_type(16))) float f32x16;
typedef __attribute__((ext_vector_type(4))) unsigned short us4;
typedef __attribute__((ext_vector_type(4))) unsigned int u32x4;
typedef __attribute__((ext_vector_type(2))) __bf16 bf16x2;

#define LOG2E 1.4426950408889634f

// f32 -> bf16 RNE via native cast (clang emits v_cvt_pk_bf16_f32 pairs).
__device__ __forceinline__ unsigned short f2bf(float f) {
    return __builtin_bit_cast(unsigned short, static_cast<__bf16>(f));
}
__device__ __forceinline__ unsigned int packbf(float lo, float hi_) {
    f32x2 v; v[0] = lo; v[1] = hi_;
    return __builtin_bit_cast(unsigned int, __builtin_convertvector(v, bf16x2));
}

// ---------------- 4 weight matrices fp32 -> bf16, one launch ----------------
// Wq (g==2) is pre-scaled by log2e so attention logits arrive in exp2 domain.
__global__ __launch_bounds__(256) void cvt_w4_kernel(const float* __restrict__ w0,
                                                     const float* __restrict__ w1,
                                                     const float* __restrict__ w2,
                                                     const float* __restrict__ w3,
                                                     unsigned short* __restrict__ d0,
                                                     unsigned short* __restrict__ d1,
                                                     unsigned short* __restrict__ d2,
                                                     unsigned short* __restrict__ d3) {
    const int g = blockIdx.x >> 10;            // which weight (1024 blocks each)
    const float* src = g == 0 ? w0 : g == 1 ? w1 : g == 2 ? w2 : w3;
    unsigned short* dst = g == 0 ? d0 : g == 1 ? d1 : g == 2 ? d2 : d3;
    const float scl = (g == 2) ? LOG2E : 1.0f;
    const int i = ((blockIdx.x & 1023) * 256 + threadIdx.x) * 4;
    f32x4 f = *(const f32x4*)(src + i);
    us4 o;
#pragma unroll
    for (int j = 0; j < 4; ++j) o[j] = f2bf(f[j] * scl);
    *(us4*)(dst + i) = o;
}

// ---------------- GEMM: C[M,N] = A[M,K] @ W[N,K]^T ----------------
// M=8192, N=1024, K=1024. 128x128 tile, BK=32, 4 waves (each 64x64).
// Reg-prefetch (T14): next BK-chunk loads issued in the compute shadow.
// A_IS_F32: A is fp32 (converted to bf16 during LDS write), else bf16.
// OUT_MODE 0: bf16 [B,H,S,D]. OUT_MODE 1: fp32 [M,N]+bias.
// OUT_MODE 2: bf16 V^T kv-blocked [B,H,S/64,D,64].
template<int A_IS_F32, int OUT_MODE>
__global__ __launch_bounds__(256) void gemm_bt(const void* __restrict__ Aptr,
                                               const unsigned short* __restrict__ Wp,
                                               void* __restrict__ Cp,
                                               const float* __restrict__ bias) {
    constexpr int K = 1024;
    __shared__ unsigned short As[128][40];  // pad 32->40: 2-way (free) bank pattern
    __shared__ unsigned short Bs[128][40];
    const int tid = threadIdx.x;
    const int bm = blockIdx.x, bn = blockIdx.y;
    const int lane = tid & 63, wid = tid >> 6;
    const int lr = lane & 15, lg = lane >> 4;
    const int wr = wid >> 1, wc = wid & 1;
    const int srow = tid >> 1, shalf = tid & 1;

    f32x4 acc[4][4];
#pragma unroll
    for (int a = 0; a < 4; ++a)
#pragma unroll
        for (int b = 0; b < 4; ++b) acc[a][b] = (f32x4){0.f, 0.f, 0.f, 0.f};

    const size_t arow = (size_t)(bm * 128 + srow) * K + shalf * 16;
    const size_t brow = (size_t)(bn * 128 + srow) * K + shalf * 16;
    const float*          apF = (const float*)Aptr + arow;
    const unsigned short* apH = (const unsigned short*)Aptr + arow;
    const unsigned short* bp  = Wp + brow;

    // prefetch registers (prologue: chunk k0=0)
    f32x4 pa0, pa1, pa2, pa3;
    short8 pah0, pah1, pb0, pb1;
    if (A_IS_F32) {
        pa0 = *(const f32x4*)(apF);
        pa1 = *(const f32x4*)(apF + 4);
        pa2 = *(const f32x4*)(apF + 8);
        pa3 = *(const f32x4*)(apF + 12);
    } else {
        pah0 = *(const short8*)(apH);
        pah1 = *(const short8*)(apH + 8);
    }
    pb0 = *(const short8*)(bp);
    pb1 = *(const short8*)(bp + 8);

    for (int k0 = 0; k0 < K; k0 += 32) {
        __syncthreads();  // all waves done reading previous LDS contents
        if (A_IS_F32) {
            short8 p0, p1;
#pragma unroll
            for (int j = 0; j < 4; ++j) {
                p0[j]     = (short)f2bf(pa0[j]);
                p0[j + 4] = (short)f2bf(pa1[j]);
                p1[j]     = (short)f2bf(pa2[j]);
                p1[j + 4] = (short)f2bf(pa3[j]);
            }
            *(short8*)&As[srow][shalf * 16]     = p0;
            *(short8*)&As[srow][shalf * 16 + 8] = p1;
        } else {
            *(short8*)&As[srow][shalf * 16]     = pah0;
            *(short8*)&As[srow][shalf * 16 + 8] = pah1;
        }
        *(short8*)&Bs[srow][shalf * 16]     = pb0;
        *(short8*)&Bs[srow][shalf * 16 + 8] = pb1;
        __syncthreads();

        // issue next chunk's loads; they fly under the MFMA section below
        if (k0 + 32 < K) {
            const int kn = k0 + 32;
            if (A_IS_F32) {
                pa0 = *(const f32x4*)(apF + kn);
                pa1 = *(const f32x4*)(apF + kn + 4);
                pa2 = *(const f32x4*)(apF + kn + 8);
                pa3 = *(const f32x4*)(apF + kn + 12);
            } else {
                pah0 = *(const short8*)(apH + kn);
                pah1 = *(const short8*)(apH + kn + 8);
            }
            pb0 = *(const short8*)(bp + kn);
            pb1 = *(const short8*)(bp + kn + 8);
        }

        short8 af[4], bfr[4];
#pragma unroll
        for (int mi = 0; mi < 4; ++mi) af[mi]  = *(const short8*)&As[wr * 64 + mi * 16 + lr][lg * 8];
#pragma unroll
        for (int ni = 0; ni < 4; ++ni) bfr[ni] = *(const short8*)&Bs[wc * 64 + ni * 16 + lr][lg * 8];
#pragma unroll
        for (int mi = 0; mi < 4; ++mi)
#pragma unroll
            for (int ni = 0; ni < 4; ++ni)
                acc[mi][ni] = __builtin_amdgcn_mfma_f32_16x16x32_bf16(af[mi], bfr[ni], acc[mi][ni], 0, 0, 0);
    }

#pragma unroll
    for (int mi = 0; mi < 4; ++mi) {
#pragma unroll
        for (int ni = 0; ni < 4; ++ni) {
            const int n = bn * 128 + wc * 64 + ni * 16 + lr;
            if (OUT_MODE == 2) {
                // V^T kv-blocked: [B,H,S/64,D,64]; i -> s consecutive within a 64-block.
                const int m0 = bm * 128 + wr * 64 + mi * 16 + lg * 4;
                const int b = m0 >> 11, s0 = m0 & 2047;
                const int h = n >> 6, d = n & 63;
                us4 pk;
#pragma unroll
                for (int i = 0; i < 4; ++i) pk[i] = f2bf(acc[mi][ni][i]);
                const size_t idx = ((((size_t)b * NH + h) * (NS / 64) + (s0 >> 6)) * ND + d) * 64 + (s0 & 63);
                *(us4*)&((unsigned short*)Cp)[idx] = pk;
            } else {
#pragma unroll
                for (int i = 0; i < 4; ++i) {
                    const int m = bm * 128 + wr * 64 + mi * 16 + lg * 4 + i;
                    const float val = acc[mi][ni][i];
                    if (OUT_MODE == 0) {
                        const int b = m >> 11, s = m & 2047, h = n >> 6, d = n & 63;
                        ((unsigned short*)Cp)[(((size_t)b * NH + h) * NS + s) * ND + d] = f2bf(val);
                    } else {
                        ((float*)Cp)[(size_t)m * 1024 + n] = val + bias[n];
                    }
                }
            }
        }
    }
}

// ---------------- flash attention: 32x32 MFMA, in-register P, exp2 domain ----------------
// grid (S/128, B*H), 256 threads. Wave w owns q rows qw..qw+31.
// q (pre-scaled by log2e via Wq), k: [B,H,S,D] bf16. vtt: [B,H,S/64,D,64] bf16.
// KVBLK=128 staging (2 barriers per 128 kv), two 64-kv compute windows per tile.
// Swapped operands with mfma_f32_32x32x16_bf16:
//   S^T = mfma(K,Q): C col = q = lane&31, row = kv = (reg&3)+8*(reg>>2)+4*(lane>>5)
// Softmax fully in-register (exp2 domain); PV B-operand built via cvt_pk +
// v_permlane32_swap_b32 (no P LDS round-trip). Packed-f32 (v_pk_*) vector math.
__global__ __launch_bounds__(256, 3) void attn_kernel(const unsigned short* __restrict__ q,
                                                      const unsigned short* __restrict__ k,
                                                      const unsigned short* __restrict__ vtt,
                                                      unsigned short* __restrict__ o) {
    __shared__ unsigned short Kl[128][72];    // K tile [kv][d]
    __shared__ unsigned short Vl[128][72];    // V^T: rows 0-63 = block0 [d][kv], 64-127 = block1
    const int tid = threadIdx.x;
    const int lane = tid & 63, wid = tid >> 6;
    const int l31 = lane & 31, hi = lane >> 5;
    const int bh = blockIdx.y;
    const int qw = blockIdx.x * 128 + wid * 32;   // this wave's first q row
    const size_t base = (size_t)bh * NS * ND;     // same stride for q/k and vtt

    // Q fragments (B-operand): col = q = l31, k = d = 16m + 8*hi + j
    short8 qf[4];
    {
        const unsigned short* qp = q + base + (size_t)(qw + l31) * ND + 8 * hi;
#pragma unroll
        for (int m = 0; m < 4; ++m) qf[m] = *(const short8*)(qp + 16 * m);
    }

    float m_run = -__builtin_inff(), l_run = 0.f;   // exp2-domain state for q-row l31
    f32x16 oa0, oa1, fz;
#pragma unroll
    for (int i = 0; i < 16; ++i) { oa0[i] = 0.f; oa1[i] = 0.f; fz[i] = 0.f; }

    // staging: 2x 8KB chunks per tensor per tile; 32B per thread per chunk
    const int strow = tid >> 2, stcol = (tid & 3) * 16;
    const unsigned short* ks = k   + base + tid * 16;   // + kv0*ND per tile
    const unsigned short* vs = vtt + base + tid * 16;

    // prologue: prefetch tile kv0=0 (both 64-kv chunks) into regs (T14)
    short8 kr00 = *(const short8*)(ks);
    short8 kr01 = *(const short8*)(ks + 8);
    short8 kr10 = *(const short8*)(ks + 4096);
    short8 kr11 = *(const short8*)(ks + 4096 + 8);
    short8 vr00 = *(const short8*)(vs);
    short8 vr01 = *(const short8*)(vs + 8);
    short8 vr10 = *(const short8*)(vs + 4096);
    short8 vr11 = *(const short8*)(vs + 4096 + 8);

    for (int kv0 = 0; kv0 < NS; kv0 += 128) {
        __syncthreads();                          // all waves done reading prev tile
        *(short8*)&Kl[strow][stcol]          = kr00;   // vmcnt wait lands here (1 tile later)
        *(short8*)&Kl[strow][stcol + 8]      = kr01;
        *(short8*)&Kl[64 + strow][stcol]     = kr10;
        *(short8*)&Kl[64 + strow][stcol + 8] = kr11;
        *(short8*)&Vl[strow][stcol]          = vr00;
        *(short8*)&Vl[strow][stcol + 8]      = vr01;
        *(short8*)&Vl[64 + strow][stcol]     = vr10;
        *(short8*)&Vl[64 + strow][stcol + 8] = vr11;
        __syncthreads();

        // issue next tile's loads; they fly under this tile's two compute windows
        if (kv0 + 128 < NS) {
            const unsigned short* ks2 = ks + (size_t)(kv0 + 128) * ND;
            const unsigned short* vs2 = vs + (size_t)(kv0 + 128) * ND;
            kr00 = *(const short8*)(ks2);
            kr01 = *(const short8*)(ks2 + 8);
            kr10 = *(const short8*)(ks2 + 4096);
            kr11 = *(const short8*)(ks2 + 4096 + 8);
            vr00 = *(const short8*)(vs2);
            vr01 = *(const short8*)(vs2 + 8);
            vr10 = *(const short8*)(vs2 + 4096);
            vr11 = *(const short8*)(vs2 + 4096 + 8);
        }

#pragma unroll
        for (int w = 0; w < 2; ++w) {
            const int rb = w << 6;   // window row base in Kl/Vl

            // S^T = K·Q^T: two 32-kv subtiles, K=64 via 4 chained mfma each
            f32x16 st0, st1;
            __builtin_amdgcn_s_setprio(1);
            {
                short8 kf;
                kf = *(const short8*)&Kl[rb + l31][8 * hi];
                st0 = __builtin_amdgcn_mfma_f32_32x32x16_bf16(kf, qf[0], fz, 0, 0, 0);
                kf = *(const short8*)&Kl[rb + l31][16 + 8 * hi];
                st0 = __builtin_amdgcn_mfma_f32_32x32x16_bf16(kf, qf[1], st0, 0, 0, 0);
                kf = *(const short8*)&Kl[rb + l31][32 + 8 * hi];
                st0 = __builtin_amdgcn_mfma_f32_32x32x16_bf16(kf, qf[2], st0, 0, 0, 0);
                kf = *(const short8*)&Kl[rb + l31][48 + 8 * hi];
                st0 = __builtin_amdgcn_mfma_f32_32x32x16_bf16(kf, qf[3], st0, 0, 0, 0);
                kf = *(const short8*)&Kl[rb + 32 + l31][8 * hi];
                st1 = __builtin_amdgcn_mfma_f32_32x32x16_bf16(kf, qf[0], fz, 0, 0, 0);
                kf = *(const short8*)&Kl[rb + 32 + l31][16 + 8 * hi];
                st1 = __builtin_amdgcn_mfma_f32_32x32x16_bf16(kf, qf[1], st1, 0, 0, 0);
                kf = *(const short8*)&Kl[rb + 32 + l31][32 + 8 * hi];
                st1 = __builtin_amdgcn_mfma_f32_32x32x16_bf16(kf, qf[2], st1, 0, 0, 0);
                kf = *(const short8*)&Kl[rb + 32 + l31][48 + 8 * hi];
                st1 = __builtin_amdgcn_mfma_f32_32x32x16_bf16(kf, qf[3], st1, 0, 0, 0);
            }
            __builtin_amdgcn_s_setprio(0);

            // online softmax, exp2 domain (logits pre-scaled by log2e via Wq)
            float pm = st0[0];
#pragma unroll
            for (int i = 1; i < 16; ++i) pm = fmaxf(pm, st0[i]);   // compiler forms v_max3
#pragma unroll
            for (int i = 0; i < 16; ++i) pm = fmaxf(pm, st1[i]);
            pm = fmaxf(pm, __shfl_xor(pm, 32, 64));
            if (!__all(pm <= m_run)) {   // T13(THR=0): skip path multiplied by exactly 1.0
                const float mn = fmaxf(m_run, pm);
                const float alpha = exp2f(m_run - mn);
                m_run = mn;
                l_run *= alpha;
                oa0 = oa0 * alpha;       // v_pk_mul_f32 x8
                oa1 = oa1 * alpha;
            }
            st0 = st0 - m_run;           // v_pk_add_f32 (neg) x8
            st1 = st1 - m_run;
#pragma unroll
            for (int i = 0; i < 16; ++i) st0[i] = exp2f(st0[i]);
#pragma unroll
            for (int i = 0; i < 16; ++i) st1[i] = exp2f(st1[i]);
            {   // packed tree sum of 32 exps
                f32x16 sv = st0 + st1;
                f32x8 s8 = __builtin_shufflevector(sv, sv, 0, 1, 2, 3, 4, 5, 6, 7)
                         + __builtin_shufflevector(sv, sv, 8, 9, 10, 11, 12, 13, 14, 15);
                f32x4 s4 = __builtin_shufflevector(s8, s8, 0, 1, 2, 3)
                         + __builtin_shufflevector(s8, s8, 4, 5, 6, 7);
                f32x2 s2 = __builtin_shufflevector(s4, s4, 0, 1)
                         + __builtin_shufflevector(s4, s4, 2, 3);
                float rs = s2[0] + s2[1];
                rs += __shfl_xor(rs, 32, 64);
                l_run += rs;
            }

            // P -> PV B-operand fragments, fully in-register (T12)
            short8 pf0, pf1, pf2, pf3;
#define MKPF(PF, SV, RB) { \
            unsigned int wa = packbf(SV[RB + 0], SV[RB + 1]); \
            unsigned int wb = packbf(SV[RB + 2], SV[RB + 3]); \
            unsigned int wc = packbf(SV[RB + 4], SV[RB + 5]); \
            unsigned int wd = packbf(SV[RB + 6], SV[RB + 7]); \
            asm("v_permlane32_swap_b32 %0, %1" : "+v"(wa), "+v"(wc)); \
            asm("v_permlane32_swap_b32 %0, %1" : "+v"(wb), "+v"(wd)); \
            u32x4 pw; pw[0] = wa; pw[1] = wb; pw[2] = wc; pw[3] = wd; \
            PF = __builtin_bit_cast(short8, pw); }
            MKPF(pf0, st0, 0)   // kv  0..15 of window
            MKPF(pf1, st0, 8)   // kv 16..31
            MKPF(pf2, st1, 0)   // kv 32..47
            MKPF(pf3, st1, 8)   // kv 48..63
#undef MKPF

            // O^T += V^T · P^T  (A row = d, B col = q)
            __builtin_amdgcn_s_setprio(1);
            {
                short8 vf;
                vf = *(const short8*)&Vl[rb + l31][8 * hi];
                oa0 = __builtin_amdgcn_mfma_f32_32x32x16_bf16(vf, pf0, oa0, 0, 0, 0);
                vf = *(const short8*)&Vl[rb + l31][16 + 8 * hi];
                oa0 = __builtin_amdgcn_mfma_f32_32x32x16_bf16(vf, pf1, oa0, 0, 0, 0);
                vf = *(const short8*)&Vl[rb + l31][32 + 8 * hi];
                oa0 = __builtin_amdgcn_mfma_f32_32x32x16_bf16(vf, pf2, oa0, 0, 0, 0);
                vf = *(const short8*)&Vl[rb + l31][48 + 8 * hi];
                oa0 = __builtin_amdgcn_mfma_f32_32x32x16_bf16(vf, pf3, oa0, 0, 0, 0);
                vf = *(const short8*)&Vl[rb + 32 + l31][8 * hi];
                oa1 = __builtin_amdgcn_mfma_f32_32x32x16_bf16(vf, pf0, oa1, 0, 0, 0);
                vf = *(const short8*)&Vl[rb + 32 + l31][16 + 8 * hi];
                oa1 = __builtin_amdgcn_mfma_f32_32x32x16_bf16(vf, pf1, oa1, 0, 0, 0);
                vf = *(const short8*)&Vl[rb + 32 + l31][32 + 8 * hi];
                oa1 = __builtin_amdgcn_mfma_f32_32x32x16_bf16(vf, pf2, oa1, 0, 0, 0);
                vf = *(const short8*)&Vl[rb + 32 + l31][48 + 8 * hi];
                oa1 = __builtin_amdgcn_mfma_f32_32x32x16_bf16(vf, pf3, oa1, 0, 0, 0);
            }
            __builtin_amdgcn_s_setprio(0);
        }
    }

    // epilogue: C reg r -> d = 32*t + 8*(r>>2) + 4*hi + (r&3); s = qw + l31
    const int b = bh >> 4, h = bh & 15;
    const float scl = 0.125f / l_run;   // softmax BEFORE scaling -> /8 here
    unsigned short* op = o + (((size_t)b * NS + (qw + l31)) * NH + h) * ND;
#pragma unroll
    for (int rq = 0; rq < 4; ++rq) {
        us4 p0, p1;
#pragma unroll
        for (int i = 0; i < 4; ++i) {
            p0[i] = f2bf(oa0[4 * rq + i] * scl);
            p1[i] = f2bf(oa1[4 * rq + i] * scl);
        }
        *(us4*)&op[8 * rq + 4 * hi]      = p0;
        *(us4*)&op[32 + 8 * rq + 4 * hi] = p1;
    }
}

extern "C" void kernel_launch(void* const* d_in, const int* in_sizes, int n_in,
                              void* d_out, int out_size, void* d_ws, size_t ws_size,
                              hipStream_t stream) {
    (void)in_sizes; (void)n_in; (void)out_size; (void)ws_size;
    const float* values  = (const float*)d_in[0];
    const float* keys    = (const float*)d_in[1];
    const float* queries = (const float*)d_in[2];
    const float* Wv = (const float*)d_in[3];
    const float* Wk = (const float*)d_in[4];
    const float* Wq = (const float*)d_in[5];
    const float* Wo = (const float*)d_in[6];
    const float* bo = (const float*)d_in[7];

    uint8_t* ws = (uint8_t*)d_ws;
    const size_t MB = (size_t)1 << 20;
    unsigned short* wvb = (unsigned short*)(ws + 0 * MB);
    unsigned short* wkb = (unsigned short*)(ws + 2 * MB);
    unsigned short* wqb = (unsigned short*)(ws + 4 * MB);
    unsigned short* wob = (unsigned short*)(ws + 6 * MB);
    unsigned short* qb  = (unsigned short*)(ws + 8 * MB);   // [B,H,S,D] bf16 (log2e-scaled), 16 MB
    unsigned short* kb  = (unsigned short*)(ws + 24 * MB);  // [B,H,S,D] bf16
    unsigned short* vtb = (unsigned short*)(ws + 40 * MB);  // [B,H,S/64,D,64] bf16 (V^T kv-blocked)
    unsigned short* ab  = (unsigned short*)(ws + 56 * MB);  // [B,S,H,D] bf16, 16 MB

    cvt_w4_kernel<<<4096, 256, 0, stream>>>(Wv, Wk, Wq, Wo, wvb, wkb, wqb, wob);

    dim3 gg(64, 8);  // (M/128, N/128)
    gemm_bt<1, 0><<<gg, 256, 0, stream>>>(queries, wqb, qb,  nullptr);
    gemm_bt<1, 0><<<gg, 256, 0, stream>>>(keys,    wkb, kb,  nullptr);
    gemm_bt<1, 2><<<gg, 256, 0, stream>>>(values,  wvb, vtb, nullptr);

    attn_kernel<<<dim3(16, 64), 256, 0, stream>>>(qb, kb, vtb, ab);

    gemm_bt<0, 1><<<gg, 256, 0, stream>>>(ab, wob, d_out, bo);
}